// Round 2
// baseline (109.989 us; speedup 1.0000x reference)
//
#include <hip/hip_runtime.h>
#include <stdint.h>

#define NB   8
#define NN   2048
#define FIN  128
#define FOUT 64
#define NEGINF (-9e15f)

__device__ __forceinline__ uint32_t rotl32(uint32_t x, uint32_t r) {
  return (x << r) | (x >> (32u - r));
}

// JAX threefry2x32 with key = (0, 42)  [jax.random.key(42) -> data (0,42)]
__device__ __forceinline__ void threefry_0_42(uint32_t x0, uint32_t x1,
                                              uint32_t& o0, uint32_t& o1) {
  const uint32_t k0 = 0u, k1 = 42u;
  const uint32_t k2 = 0x1BD11BDAu ^ k0 ^ k1;
  x0 += k0; x1 += k1;
#define TFR(r) { x0 += x1; x1 = rotl32(x1, r); x1 ^= x0; }
  TFR(13u) TFR(15u) TFR(26u) TFR(6u)   x0 += k1; x1 += k2 + 1u;
  TFR(17u) TFR(29u) TFR(16u) TFR(24u)  x0 += k2; x1 += k0 + 2u;
  TFR(13u) TFR(15u) TFR(26u) TFR(6u)   x0 += k0; x1 += k1 + 3u;
  TFR(17u) TFR(29u) TFR(16u) TFR(24u)  x0 += k1; x1 += k2 + 4u;
  TFR(13u) TFR(15u) TFR(26u) TFR(6u)   x0 += k2; x1 += k0 + 5u;
#undef TFR
  o0 = x0; o1 = x1;
}

// Partitionable-threefry keep bit for flat element v (v < 2^32):
// bits = o0 ^ o1 of threefry(key, hi32(v)=0, lo32(v)=v); keep iff bit31==0.
__device__ __forceinline__ bool keep_bit(uint32_t v) {
  uint32_t o0, o1;
  threefry_0_42(0u, v, o0, o1);
  return !((o0 ^ o1) >> 31);
}

__device__ __forceinline__ void online_upd(float& m, float& s, float e) {
  float mn = fmaxf(m, e);
  s = s * __expf(m - mn) + __expf(e - mn);
  m = mn;
}

__device__ __forceinline__ void merge_ms(float& m, float& s, float mo, float so) {
  float mn = fmaxf(m, mo);
  s = s * __expf(m - mn) + so * __expf(mo - mn);
  m = mn;
}

// Kernel A: Wh = h @ W  [B*N,64],  Wh1 = Wh@a[:64],  Wh2 = Wh@a[64:]
__global__ __launch_bounds__(256) void wh_kernel(
    const float* __restrict__ h, const float* __restrict__ W,
    const float* __restrict__ a, float* __restrict__ Wh,
    float* __restrict__ Wh1, float* __restrict__ Wh2) {
  __shared__ float wLds[FIN * FOUT];   // 32 KB
  __shared__ float hLds[4][FIN];       // 2 KB
  const int t = threadIdx.x;
  const int wv = t >> 6, lane = t & 63;
  for (int idx = t; idx < FIN * FOUT; idx += 256) wLds[idx] = W[idx];
  const int row = blockIdx.x * 4 + wv;           // [0, 16384)
  {
    float2 v = *reinterpret_cast<const float2*>(&h[(size_t)row * FIN + lane * 2]);
    hLds[wv][lane * 2]     = v.x;
    hLds[wv][lane * 2 + 1] = v.y;
  }
  __syncthreads();
  float acc = 0.f;
#pragma unroll 8
  for (int k = 0; k < FIN; ++k) acc += hLds[wv][k] * wLds[k * FOUT + lane];
  Wh[(size_t)row * FOUT + lane] = acc;
  float x1 = acc * a[lane];
  float x2 = acc * a[FOUT + lane];
#pragma unroll
  for (int off = 32; off >= 1; off >>= 1) {
    x1 += __shfl_xor(x1, off);
    x2 += __shfl_xor(x2, off);
  }
  if (lane == 0) { Wh1[row] = x1; Wh2[row] = x2; }
}

// Kernel B: per block: batch pair (b, b+4), one row i.
// pass 1: stream adj row + Wh2, online (m,s) with adj mask; stash
//         (adj && keep) ? e : -9e15 in LDS (keep from partitionable threefry).
// pass 2: c = exp(e-m)*2/s, ballot-compact survivors, sparse PV.
__global__ __launch_bounds__(256) void attn_kernel(
    const int* __restrict__ adj, const float* __restrict__ Wh,
    const float* __restrict__ Wh1, const float* __restrict__ Wh2,
    float* __restrict__ out) {
  __shared__ __align__(16) float eL[2][NN];       // 16 KB
  __shared__ float mred[2][4], sred[2][4];
  __shared__ float accL[2][4][FOUT];              // 2 KB

  const int i = blockIdx.x & (NN - 1);
  const int b = blockIdx.x >> 11;                 // 0..3
  const int b2 = b + 4;
  const int t = threadIdx.x;
  const int wv = t >> 6, lane = t & 63;

  const float wh1_0 = Wh1[b * NN + i];
  const float wh1_1 = Wh1[b2 * NN + i];
  const size_t adjBase0 = ((size_t)b * NN + i) * NN;
  const size_t adjBase1 = ((size_t)b2 * NN + i) * NN;

  float m0 = -3.0e38f, s0 = 0.f, m1 = -3.0e38f, s1 = 0.f;

  for (int j0 = 0; j0 < NN; j0 += 1024) {
    const int j = j0 + t * 4;
    const int4   av0 = *reinterpret_cast<const int4*>(adj + adjBase0 + j);
    const int4   av1 = *reinterpret_cast<const int4*>(adj + adjBase1 + j);
    const float4 wv0 = *reinterpret_cast<const float4*>(Wh2 + (size_t)b * NN + j);
    const float4 wv1 = *reinterpret_cast<const float4*>(Wh2 + (size_t)b2 * NN + j);
    const int aa0[4] = {av0.x, av0.y, av0.z, av0.w};
    const int aa1[4] = {av1.x, av1.y, av1.z, av1.w};
    const float w0[4] = {wv0.x, wv0.y, wv0.z, wv0.w};
    const float w1[4] = {wv1.x, wv1.y, wv1.z, wv1.w};
    // flat element index: v = b*2^22 + i*2^11 + j  (batch b2 = v + 2^24)
    const uint32_t vb0 = ((uint32_t)b << 22) | ((uint32_t)i << 11) | (uint32_t)j;
    const uint32_t vb1 = vb0 + (1u << 24);
#pragma unroll
    for (int e = 0; e < 4; ++e) {
      const bool k0 = keep_bit(vb0 + (uint32_t)e);
      const bool k1 = keep_bit(vb1 + (uint32_t)e);
      // batch b
      float x = wh1_0 + w0[e];
      x = (x < 0.f) ? 0.2f * x : x;
      const float xm = (aa0[e] > 0) ? x : NEGINF;
      online_upd(m0, s0, xm);
      eL[0][j + e] = (aa0[e] > 0 && k0) ? x : NEGINF;
      // batch b+4
      float y = wh1_1 + w1[e];
      y = (y < 0.f) ? 0.2f * y : y;
      const float ym = (aa1[e] > 0) ? y : NEGINF;
      online_upd(m1, s1, ym);
      eL[1][j + e] = (aa1[e] > 0 && k1) ? y : NEGINF;
    }
  }

  // wave-level (m,s) butterfly reduce
#pragma unroll
  for (int off = 1; off < 64; off <<= 1) {
    float mo = __shfl_xor(m0, off), so = __shfl_xor(s0, off);
    merge_ms(m0, s0, mo, so);
    mo = __shfl_xor(m1, off); so = __shfl_xor(s1, off);
    merge_ms(m1, s1, mo, so);
  }
  if (lane == 0) {
    mred[0][wv] = m0; sred[0][wv] = s0;
    mred[1][wv] = m1; sred[1][wv] = s1;
  }
  __syncthreads();   // also covers eL writes -> pass-2 reads
  m0 = mred[0][0]; s0 = sred[0][0];
  m1 = mred[1][0]; s1 = sred[1][0];
#pragma unroll
  for (int w = 1; w < 4; ++w) {
    merge_ms(m0, s0, mred[0][w], sred[0][w]);
    merge_ms(m1, s1, mred[1][w], sred[1][w]);
  }
  const float inv0 = 2.0f / s0;   // dropout scale 1/(1-p)=2 folded in
  const float inv1 = 2.0f / s1;

  // pass 2: sparse PV
  float acc0 = 0.f, acc1 = 0.f;
  for (int j0 = wv * 64; j0 < NN; j0 += 256) {
    const int j = j0 + lane;
    const float c0 = __expf(eL[0][j] - m0) * inv0;
    const float c1 = __expf(eL[1][j] - m1) * inv1;
    unsigned long long act = __ballot(c0 > 1e-12f);
    while (act) {
      const int src = __builtin_ctzll(act);
      const float c = __shfl(c0, src);
      acc0 += c * Wh[((size_t)b * NN + (j0 + src)) * FOUT + lane];
      act &= act - 1;
    }
    act = __ballot(c1 > 1e-12f);
    while (act) {
      const int src = __builtin_ctzll(act);
      const float c = __shfl(c1, src);
      acc1 += c * Wh[((size_t)b2 * NN + (j0 + src)) * FOUT + lane];
      act &= act - 1;
    }
  }
  accL[0][wv][lane] = acc0;
  accL[1][wv][lane] = acc1;
  __syncthreads();
  if (t < 128) {
    const int bb = t >> 6, f = t & 63;
    const float r = accL[bb][0][f] + accL[bb][1][f] + accL[bb][2][f] + accL[bb][3][f];
    const int bo = (bb == 0) ? b : b2;
    out[((size_t)bo * NN + i) * FOUT + f] = r;
  }
}

extern "C" void kernel_launch(void* const* d_in, const int* in_sizes, int n_in,
                              void* d_out, int out_size, void* d_ws, size_t ws_size,
                              hipStream_t stream) {
  const float* h   = (const float*)d_in[0];
  const int*   adj = (const int*)d_in[1];
  const float* W   = (const float*)d_in[2];
  const float* a   = (const float*)d_in[3];
  float* out = (float*)d_out;
  float* ws  = (float*)d_ws;

  float* Wh  = ws;                                 // 16384*64 floats
  float* Wh1 = ws + (size_t)NB * NN * FOUT;        // 16384
  float* Wh2 = Wh1 + NB * NN;                      // 16384

  wh_kernel<<<dim3((NB * NN) / 4), dim3(256), 0, stream>>>(h, W, a, Wh, Wh1, Wh2);
  attn_kernel<<<dim3((NB / 2) * NN), dim3(256), 0, stream>>>(adj, Wh, Wh1, Wh2, out);
}